// Round 3
// baseline (3493.169 us; speedup 1.0000x reference)
//
#include <hip/hip_runtime.h>
#include <hip/hip_cooperative_groups.h>

namespace cg = cooperative_groups;

#define BB 256
#define SS 64
#define HH 512
#define VV 32000

typedef unsigned short u16;
typedef __attribute__((ext_vector_type(8))) short bf16x8;   // 8 bf16 = 4 VGPRs
typedef __attribute__((ext_vector_type(4))) float f32x4;    // MFMA 16x16 C/D

__device__ __forceinline__ float sigm(float x) { return 1.0f / (1.0f + __expf(-x)); }
__device__ __forceinline__ float tanh_fast(float x) { return 1.0f - 2.0f / (__expf(2.0f * x) + 1.0f); }
__device__ __forceinline__ u16 f2bf(float f) {              // RNE fp32 -> bf16
    unsigned u = __float_as_uint(f);
    return (u16)((u + 0x7fffu + ((u >> 16) & 1u)) >> 16);
}
__device__ __forceinline__ bf16x8 ld_cvt8(const float* s) { // 8 fp32 -> bf16x8
    float4 v0 = *(const float4*)s, v1 = *(const float4*)(s + 4);
    bf16x8 b;
    b[0] = (short)f2bf(v0.x); b[1] = (short)f2bf(v0.y);
    b[2] = (short)f2bf(v0.z); b[3] = (short)f2bf(v0.w);
    b[4] = (short)f2bf(v1.x); b[5] = (short)f2bf(v1.y);
    b[6] = (short)f2bf(v1.z); b[7] = (short)f2bf(v1.w);
    return b;
}

#define MFMA(a, b, c) __builtin_amdgcn_mfma_f32_16x16x32_bf16(a, b, c, 0, 0, 0)

// ---------------------------------------------------------------------------
// pack_k: one-time swizzle into MFMA fragment layouts (wave-task based).
// ---------------------------------------------------------------------------
__global__ __launch_bounds__(256)
void pack_k(const int* __restrict__ x, const float* __restrict__ W_emb,
            const float* __restrict__ Wih_f, const float* __restrict__ Whh_f,
            const float* __restrict__ Wih_b, const float* __restrict__ Whh_b,
            const float* __restrict__ Wih_c, const float* __restrict__ Whh_c,
            u16* __restrict__ Xfrag, u16* __restrict__ Wfsw,
            u16* __restrict__ Wbsw, u16* __restrict__ Wcsw)
{
    const int lane = threadIdx.x & 63;
    const int l15 = lane & 15, quad = lane >> 4;
    const int gw0 = blockIdx.x * 4 + (threadIdx.x >> 6);
    const int nw = gridDim.x * 4;
    for (int task = gw0; task < 40960; task += nw) {
        const float* src; u16* dst; float scale = 1.f;
        if (task < 16384) {                         // Xfrag: (s, mt, kc)
            int s = task >> 8, rem = task & 255, mt = rem >> 4, kc = rem & 15;
            int b = mt * 16 + l15;
            int tok = x[s * 256 + b];               // raw reshape: row = s*256+b
            scale = (tok == 0) ? 0.f : 1.f;         // padding_idx=0
            src = W_emb + (size_t)tok * 512 + kc * 32 + quad * 8;
            dst = Xfrag + ((size_t)(s * 16 + mt) * 16 + kc) * 512 + (size_t)lane * 8;
        } else if (task < 24576) {                  // Wf / Wb: (which, ut, kc, g)
            int e = task - 16384;
            int which = e >> 12; e &= 4095;
            int ut = e >> 7, rem = e & 127, kc = rem >> 2, g = rem & 3;
            int row = g * 512 + ut * 16 + l15;
            int k0 = kc * 32 + quad * 8;
            const float* Wih = which ? Wih_b : Wih_f;
            const float* Whh = which ? Whh_b : Whh_f;
            src = (k0 < 512) ? (Wih + (size_t)row * 512 + k0)
                             : (Whh + (size_t)row * 512 + (k0 - 512));
            u16* W = which ? Wbsw : Wfsw;
            dst = W + ((size_t)(ut * 32 + kc) * 4 + g) * 512 + (size_t)lane * 8;
        } else {                                    // Wc: (ut, kc, g)
            int e = task - 24576;
            int ut = e >> 8, rem = e & 255, kc = rem >> 2, g = rem & 3;
            int row = g * 1024 + ut * 16 + l15;
            int k0 = kc * 32 + quad * 8;
            src = (k0 < 1024) ? (Wih_c + (size_t)row * 1024 + k0)
                              : (Whh_c + (size_t)row * 1024 + (k0 - 1024));
            dst = Wcsw + ((size_t)(ut * 64 + kc) * 4 + g) * 512 + (size_t)lane * 8;
        }
        float4 v0 = *(const float4*)src;
        float4 v1 = *(const float4*)(src + 4);
        bf16x8 o;
        o[0] = (short)f2bf(v0.x * scale); o[1] = (short)f2bf(v0.y * scale);
        o[2] = (short)f2bf(v0.z * scale); o[3] = (short)f2bf(v0.w * scale);
        o[4] = (short)f2bf(v1.x * scale); o[5] = (short)f2bf(v1.y * scale);
        o[6] = (short)f2bf(v1.z * scale); o[7] = (short)f2bf(v1.w * scale);
        *(bf16x8*)dst = o;
    }
}

// ---------------------------------------------------------------------------
// init_k: bias sums + initial states. h0 -> bf16 A-FRAGMENT layout, c -> fp32.
// ---------------------------------------------------------------------------
__global__ __launch_bounds__(256)
void init_k(const float* __restrict__ bih_f, const float* __restrict__ bhh_f,
            const float* __restrict__ bih_b, const float* __restrict__ bhh_b,
            const float* __restrict__ bih_c, const float* __restrict__ bhh_c,
            const float* __restrict__ h0f, const float* __restrict__ c0f,
            const float* __restrict__ h0b, const float* __restrict__ c0b,
            const float* __restrict__ h0c, const float* __restrict__ c0c,
            float* __restrict__ bsf, float* __restrict__ bsb, float* __restrict__ bsc,
            u16* __restrict__ hf0, u16* __restrict__ hb0, u16* __restrict__ hc0,
            float* __restrict__ cf, float* __restrict__ cb, float* __restrict__ cc)
{
    const int gid = blockIdx.x * 256 + threadIdx.x;
    if (gid < 2048)       bsf[gid] = bih_f[gid] + bhh_f[gid];
    else if (gid < 4096)  { int e = gid - 2048; bsb[e] = bih_b[e] + bhh_b[e]; }
    else if (gid < 8192)  { int e = gid - 4096; bsc[e] = bih_c[e] + bhh_c[e]; }
    const int stride = gridDim.x * 256;
    for (int i = gid; i < 131072; i += stride) {
        int b = i >> 9, k = i & 511;
        int dst = ((b >> 4) * 16 + (k >> 5)) * 512 + (((b & 15) + (((k >> 3) & 3) << 4)) << 3) + (k & 7);
        hf0[dst] = f2bf(h0f[i]);
        hb0[dst] = f2bf(h0b[i]);
        cf[i] = c0f[i];
        cb[i] = c0b[i];
    }
    for (int i = gid; i < 262144; i += stride) {
        int b = i >> 10, k = i & 1023;
        int dst = ((b >> 4) * 32 + (k >> 5)) * 512 + (((b & 15) + (((k >> 3) & 3) << 4)) << 3) + (k & 7);
        hc0[dst] = f2bf(h0c[i]);
        cc[i] = c0c[i];
    }
}

// ---------------------------------------------------------------------------
// seq_k: persistent cooperative kernel — all 65 step iterations in one launch.
//  256 blocks (1/CU, LDS-limited), 4 waves each. Same block role mapping as
//  step_k. Weights LDS-resident (fb: full 128KB; comb: first half 128KB,
//  second half streamed double-buffered). c-state lives in registers for the
//  whole sequence. grid.sync() between steps gives cross-XCD h visibility.
// ---------------------------------------------------------------------------
__global__ __launch_bounds__(256, 1)
void seq_k(const u16* __restrict__ Xfrag,
           const u16* __restrict__ Wfsw, const u16* __restrict__ Wbsw,
           const u16* __restrict__ Wcsw,
           const float* __restrict__ bsf, const float* __restrict__ bsb,
           const float* __restrict__ bsc,
           u16* __restrict__ hf0, u16* __restrict__ hf1,
           u16* __restrict__ hb0, u16* __restrict__ hb1,
           u16* __restrict__ hc0, u16* __restrict__ hc1,
           const float* __restrict__ c0f, const float* __restrict__ c0b,
           const float* __restrict__ c0c)
{
    __shared__ __align__(16) u16 Wlds[32][4][512];    // 128 KB resident weights
    __shared__ __align__(16) u16 Bst[2][2][4][512];   // 16 KB comb stream staging
    cg::grid_group grid = cg::this_grid();

    const int tid = threadIdx.x;
    const int w = tid >> 6, lane = tid & 63;
    const int l15 = lane & 15, quad = lane >> 4;
    const int xcd = blockIdx.x & 7, slot = blockIdx.x >> 3;
    const bool isfb = (slot < 16);
    const f32x4 z = {0.f, 0.f, 0.f, 0.f};

    // ---- role constants
    int ut, mt0, cell = 0;
    const u16* wsrc;
    if (isfb) {
        const int mh = slot & 1; cell = xcd >> 2;
        ut = (xcd & 3) * 8 + (slot >> 1);
        mt0 = mh * 8 + w * 2;
        wsrc = (cell ? Wbsw : Wfsw) + (size_t)ut * 65536;
    } else {
        const int cs = slot - 16; const int mh = cs & 1;
        ut = xcd * 8 + (cs >> 1);
        mt0 = mh * 8 + w * 2;
        wsrc = Wcsw + (size_t)ut * 131072;            // first half = kc 0..31
    }

    {   // ---- preload 128 KB weights (8192 x 16B, coalesced)
        const bf16x8* s = (const bf16x8*)wsrc;
        bf16x8* d = (bf16x8*)&Wlds[0][0][0];
        for (int i = tid; i < 8192; i += 256) d[i] = s[i];
    }
    __syncthreads();

    // ---- biases (regs for the whole sequence)
    const int u = ut * 16 + l15;
    float bi_, bf_, bg_, bo_;
    if (isfb) {
        const float* bs = cell ? bsb : bsf;
        bi_ = bs[u]; bf_ = bs[512 + u]; bg_ = bs[1024 + u]; bo_ = bs[1536 + u];
    } else {
        bi_ = bsc[u]; bf_ = bsc[1024 + u]; bg_ = bsc[2048 + u]; bo_ = bsc[3072 + u];
    }

    // ---- c-state in registers for the whole sequence
    float creg[8];
    {
        const float* csrc = isfb ? (cell ? c0b : c0f) : c0c;
        const int ldc = isfb ? 512 : 1024;
#pragma unroll
        for (int mi = 0; mi < 2; ++mi)
#pragma unroll
            for (int r = 0; r < 4; ++r) {
                const int b = (mt0 + mi) * 16 + quad * 4 + r;
                creg[mi * 4 + r] = csrc[(size_t)b * ldc + u];
            }
    }

    const int fragk = ut >> 1;
    const int lanehi = ((ut & 1) * 2 + (l15 >> 3)) << 4;
    const int j = l15 & 7;

    for (int t = 0; t <= SS; ++t) {
        if (isfb) {
            if (t < SS) {
                const u16* h_r = cell ? ((t & 1) ? hb1 : hb0) : ((t & 1) ? hf1 : hf0);
                u16* h_w       = cell ? ((t & 1) ? hb0 : hb1) : ((t & 1) ? hf0 : hf1);
                const int s2 = cell ? (SS - 1 - t) : t;
                const u16* xa = Xfrag + ((size_t)(s2 * 16 + mt0) * 16) * 512 + (size_t)lane * 8;
                const u16* ha = h_r + ((size_t)(mt0 * 16)) * 512 + (size_t)lane * 8;

                f32x4 acc[2][4];
#pragma unroll
                for (int mi = 0; mi < 2; ++mi)
#pragma unroll
                    for (int g = 0; g < 4; ++g) acc[mi][g] = z;

#pragma unroll
                for (int kk = 0; kk < 32; ++kk) {
                    const u16* a0p = (kk < 16) ? (xa + (size_t)kk * 512)
                                               : (ha + (size_t)(kk - 16) * 512);
                    bf16x8 a0 = *(const bf16x8*)a0p;
                    bf16x8 a1 = *(const bf16x8*)(a0p + 16 * 512);
#pragma unroll
                    for (int g = 0; g < 4; ++g) {
                        bf16x8 bg_f = *(const bf16x8*)&Wlds[kk][g][(size_t)lane * 8];
                        acc[0][g] = MFMA(a0, bg_f, acc[0][g]);
                        acc[1][g] = MFMA(a1, bg_f, acc[1][g]);
                    }
                }

#pragma unroll
                for (int mi = 0; mi < 2; ++mi) {
                    const int mt = mt0 + mi;
#pragma unroll
                    for (int r = 0; r < 4; ++r) {
                        float i_ = sigm(acc[mi][0][r] + bi_);
                        float f_ = sigm(acc[mi][1][r] + bf_);
                        float g_ = tanh_fast(acc[mi][2][r] + bg_);
                        float o_ = sigm(acc[mi][3][r] + bo_);
                        float c2 = f_ * creg[mi * 4 + r] + i_ * g_;
                        creg[mi * 4 + r] = c2;
                        h_w[(size_t)(mt * 16 + fragk) * 512 + (size_t)((quad * 4 + r) + lanehi) * 8 + j]
                            = f2bf(o_ * tanh_fast(c2));
                    }
                }
            }
        } else {
            if (t >= 1) {
                const u16* hfr = (t & 1) ? hf1 : hf0;
                const u16* hbr = (t & 1) ? hb1 : hb0;
                const u16* hcr = (t & 1) ? hc0 : hc1;   // hc[(t+1)&1]
                u16* hcw       = (t & 1) ? hc1 : hc0;   // hc[t&1]
                const u16* hfa = hfr + ((size_t)(mt0 * 16)) * 512 + (size_t)lane * 8;
                const u16* hba = hbr + ((size_t)(mt0 * 16)) * 512 + (size_t)lane * 8;
                const u16* hca = hcr + ((size_t)(mt0 * 32)) * 512 + (size_t)lane * 8;

                f32x4 acc[2][4];
#pragma unroll
                for (int mi = 0; mi < 2; ++mi)
#pragma unroll
                    for (int g = 0; g < 4; ++g) acc[mi][g] = z;

                // K 0..1023: hf | hb, B from LDS-resident Wlds, no barriers
#pragma unroll
                for (int kk = 0; kk < 32; ++kk) {
                    const int kc = kk & 15;
                    const u16* a0p = ((kk < 16) ? hfa : hba) + (size_t)kc * 512;
                    bf16x8 a0 = *(const bf16x8*)a0p;
                    bf16x8 a1 = *(const bf16x8*)(a0p + 16 * 512);
#pragma unroll
                    for (int g = 0; g < 4; ++g) {
                        bf16x8 bg_f = *(const bf16x8*)&Wlds[kk][g][(size_t)lane * 8];
                        acc[0][g] = MFMA(a0, bg_f, acc[0][g]);
                        acc[1][g] = MFMA(a1, bg_f, acc[1][g]);
                    }
                }

                // K 1024..2047: hc, B streamed (double-buffered LDS staging)
                const u16* wstream = Wcsw + (size_t)ut * 131072 + 65536
                                   + (size_t)w * 512 + (size_t)lane * 8;
                {
                    bf16x8 s0 = *(const bf16x8*)(wstream);
                    bf16x8 s1 = *(const bf16x8*)(wstream + 2048);
                    *(bf16x8*)&Bst[0][0][w][(size_t)lane * 8] = s0;
                    *(bf16x8*)&Bst[0][1][w][(size_t)lane * 8] = s1;
                    __syncthreads();
                }
                for (int p = 0; p < 16; ++p) {
                    const int cur = p & 1, nxt = cur ^ 1;
                    bf16x8 sa, sb;
                    const bool pre = (p < 15);
                    if (pre) {
                        sa = *(const bf16x8*)(wstream + (size_t)(2 * p + 2) * 2048);
                        sb = *(const bf16x8*)(wstream + (size_t)(2 * p + 3) * 2048);
                    }
                    bf16x8 a00 = *(const bf16x8*)(hca + (size_t)(2 * p) * 512);
                    bf16x8 a01 = *(const bf16x8*)(hca + 32 * 512 + (size_t)(2 * p) * 512);
                    bf16x8 a10 = *(const bf16x8*)(hca + (size_t)(2 * p + 1) * 512);
                    bf16x8 a11 = *(const bf16x8*)(hca + 32 * 512 + (size_t)(2 * p + 1) * 512);
#pragma unroll
                    for (int g = 0; g < 4; ++g) {
                        bf16x8 b0 = *(const bf16x8*)&Bst[cur][0][g][(size_t)lane * 8];
                        bf16x8 b1 = *(const bf16x8*)&Bst[cur][1][g][(size_t)lane * 8];
                        acc[0][g] = MFMA(a00, b0, acc[0][g]);
                        acc[1][g] = MFMA(a01, b0, acc[1][g]);
                        acc[0][g] = MFMA(a10, b1, acc[0][g]);
                        acc[1][g] = MFMA(a11, b1, acc[1][g]);
                    }
                    if (pre) {
                        *(bf16x8*)&Bst[nxt][0][w][(size_t)lane * 8] = sa;
                        *(bf16x8*)&Bst[nxt][1][w][(size_t)lane * 8] = sb;
                    }
                    __syncthreads();
                }

#pragma unroll
                for (int mi = 0; mi < 2; ++mi) {
                    const int mt = mt0 + mi;
#pragma unroll
                    for (int r = 0; r < 4; ++r) {
                        float i_ = sigm(acc[mi][0][r] + bi_);
                        float f_ = sigm(acc[mi][1][r] + bf_);
                        float g_ = tanh_fast(acc[mi][2][r] + bg_);
                        float o_ = sigm(acc[mi][3][r] + bo_);
                        float c2 = f_ * creg[mi * 4 + r] + i_ * g_;
                        creg[mi * 4 + r] = c2;
                        hcw[(size_t)(mt * 32 + fragk) * 512 + (size_t)((quad * 4 + r) + lanehi) * 8 + j]
                            = f2bf(o_ * tanh_fast(c2));
                    }
                }
            }
        }
        if (t < SS) grid.sync();
    }
}

// One double-buffered 2-kc GEMM period (legacy fallback step_k).
#define PERIODS(A0, A1, PS, PE, NPT)                                        \
  for (int p = (PS); p < (PE); ++p) {                                       \
    const int cur = p & 1, nxt = cur ^ 1;                                   \
    const int kl = p - (PS);                                                \
    bf16x8 sa, sb;                                                          \
    const bool pre = (p + 1 < (NPT));                                       \
    if (pre) {                                                              \
      sa = *(const bf16x8*)(wstage + (size_t)(2 * p + 2) * 2048);           \
      sb = *(const bf16x8*)(wstage + (size_t)(2 * p + 3) * 2048);           \
    }                                                                       \
    bf16x8 a00 = *(const bf16x8*)((A0) + (size_t)(2 * kl) * 512);           \
    bf16x8 a01 = *(const bf16x8*)((A1) + (size_t)(2 * kl) * 512);           \
    bf16x8 a10 = *(const bf16x8*)((A0) + (size_t)(2 * kl + 1) * 512);       \
    bf16x8 a11 = *(const bf16x8*)((A1) + (size_t)(2 * kl + 1) * 512);       \
    _Pragma("unroll")                                                       \
    for (int g = 0; g < 4; ++g) {                                           \
      bf16x8 b0 = *(const bf16x8*)&Bsh[cur][0][g][(size_t)lane * 8];        \
      bf16x8 b1 = *(const bf16x8*)&Bsh[cur][1][g][(size_t)lane * 8];        \
      acc[0][g] = MFMA(a00, b0, acc[0][g]);                                 \
      acc[1][g] = MFMA(a01, b0, acc[1][g]);                                 \
      acc[0][g] = MFMA(a10, b1, acc[0][g]);                                 \
      acc[1][g] = MFMA(a11, b1, acc[1][g]);                                 \
    }                                                                       \
    if (pre) {                                                              \
      *(bf16x8*)&Bsh[nxt][0][w][(size_t)lane * 8] = sa;                     \
      *(bf16x8*)&Bsh[nxt][1][w][(size_t)lane * 8] = sb;                     \
    }                                                                       \
    __syncthreads();                                                        \
  }

// ---------------------------------------------------------------------------
// step_k (legacy fallback, used only if cooperative launch is unavailable)
// ---------------------------------------------------------------------------
__global__ __launch_bounds__(256)
void step_k(const u16* __restrict__ Xfrag,
            const u16* __restrict__ Wfsw, const u16* __restrict__ Wbsw,
            const u16* __restrict__ Wcsw,
            const float* __restrict__ bsf, const float* __restrict__ bsb,
            const float* __restrict__ bsc,
            const u16* __restrict__ hf_r, u16* __restrict__ hf_w, float* __restrict__ cf,
            const u16* __restrict__ hb_r, u16* __restrict__ hb_w, float* __restrict__ cb,
            const u16* __restrict__ hc_r, u16* __restrict__ hc_w, float* __restrict__ cc,
            int t)
{
    __shared__ __align__(16) u16 Bsh[2][2][4][512];   // 16 KB
    const int tid = threadIdx.x;
    const int w = tid >> 6, lane = tid & 63;
    const int l15 = lane & 15, quad = lane >> 4;
    const int xcd = blockIdx.x & 7, slot = blockIdx.x >> 3;
    const f32x4 z = {0.f, 0.f, 0.f, 0.f};

    if (slot < 16) {
        if (t >= SS) return;
        const int mh = slot & 1, cell = xcd >> 2;
        const int ut = (xcd & 3) * 8 + (slot >> 1);
        const int mt0 = mh * 8 + w * 2;
        const u16* Wsw = cell ? Wbsw : Wfsw;
        const float* bs = cell ? bsb : bsf;
        const u16* h_r = cell ? hb_r : hf_r;
        u16* h_w = cell ? hb_w : hf_w;
        float* c = cell ? cb : cf;
        const int s2 = cell ? (SS - 1 - t) : t;

        const u16* wstage = Wsw + (size_t)ut * 65536 + (size_t)w * 512 + (size_t)lane * 8;
        const u16* xb0 = Xfrag + ((size_t)(s2 * 16 + mt0) * 16) * 512 + (size_t)lane * 8;
        const u16* xb1 = xb0 + 16 * 512;
        const u16* hp0 = h_r + ((size_t)(mt0 * 16)) * 512 + (size_t)lane * 8;
        const u16* hp1 = hp0 + 16 * 512;

        f32x4 acc[2][4];
#pragma unroll
        for (int mi = 0; mi < 2; ++mi)
#pragma unroll
            for (int g = 0; g < 4; ++g) acc[mi][g] = z;

        {
            bf16x8 s0 = *(const bf16x8*)(wstage);
            bf16x8 s1 = *(const bf16x8*)(wstage + 2048);
            *(bf16x8*)&Bsh[0][0][w][(size_t)lane * 8] = s0;
            *(bf16x8*)&Bsh[0][1][w][(size_t)lane * 8] = s1;
            __syncthreads();
        }
        PERIODS(xb0, xb1, 0, 8, 16)
        PERIODS(hp0, hp1, 8, 16, 16)

        const int u = ut * 16 + l15;
        const float bi_ = bs[u], bf_ = bs[512 + u], bg_ = bs[1024 + u], bo_ = bs[1536 + u];
        const int fragk = ut >> 1;
        const int lanehi = ((ut & 1) * 2 + (l15 >> 3)) << 4;
        const int j = l15 & 7;
#pragma unroll
        for (int mi = 0; mi < 2; ++mi) {
            const int mt = mt0 + mi;
#pragma unroll
            for (int r = 0; r < 4; ++r) {
                const int b = mt * 16 + quad * 4 + r;
                const size_t ci = (size_t)b * 512 + u;
                float i_ = sigm(acc[mi][0][r] + bi_);
                float f_ = sigm(acc[mi][1][r] + bf_);
                float g_ = tanh_fast(acc[mi][2][r] + bg_);
                float o_ = sigm(acc[mi][3][r] + bo_);
                float c2 = f_ * c[ci] + i_ * g_;
                c[ci] = c2;
                h_w[(size_t)(mt * 16 + fragk) * 512 + (size_t)((quad * 4 + r) + lanehi) * 8 + j]
                    = f2bf(o_ * tanh_fast(c2));
            }
        }
    } else {
        if (t == 0) return;
        const int cs = slot - 16;
        const int mh = cs & 1;
        const int ut = xcd * 8 + (cs >> 1);
        const int mt0 = mh * 8 + w * 2;

        const u16* wstage = Wcsw + (size_t)ut * 131072 + (size_t)w * 512 + (size_t)lane * 8;
        const u16* hfp0 = hf_r + ((size_t)(mt0 * 16)) * 512 + (size_t)lane * 8;
        const u16* hfp1 = hfp0 + 16 * 512;
        const u16* hbp0 = hb_r + ((size_t)(mt0 * 16)) * 512 + (size_t)lane * 8;
        const u16* hbp1 = hbp0 + 16 * 512;
        const u16* hcp0 = hc_r + ((size_t)(mt0 * 32)) * 512 + (size_t)lane * 8;
        const u16* hcp1 = hcp0 + 32 * 512;

        f32x4 acc[2][4];
#pragma unroll
        for (int mi = 0; mi < 2; ++mi)
#pragma unroll
            for (int g = 0; g < 4; ++g) acc[mi][g] = z;

        {
            bf16x8 s0 = *(const bf16x8*)(wstage);
            bf16x8 s1 = *(const bf16x8*)(wstage + 2048);
            *(bf16x8*)&Bsh[0][0][w][(size_t)lane * 8] = s0;
            *(bf16x8*)&Bsh[0][1][w][(size_t)lane * 8] = s1;
            __syncthreads();
        }
        PERIODS(hfp0, hfp1, 0, 8, 32)
        PERIODS(hbp0, hbp1, 8, 16, 32)
        PERIODS(hcp0, hcp1, 16, 32, 32)

        const int u = ut * 16 + l15;
        const float bi_ = bsc[u], bf_ = bsc[1024 + u], bg_ = bsc[2048 + u], bo_ = bsc[3072 + u];
        const int fragk = ut >> 1;
        const int lanehi = ((ut & 1) * 2 + (l15 >> 3)) << 4;
        const int j = l15 & 7;
#pragma unroll
        for (int mi = 0; mi < 2; ++mi) {
            const int mt = mt0 + mi;
#pragma unroll
            for (int r = 0; r < 4; ++r) {
                const int b = mt * 16 + quad * 4 + r;
                const size_t ci = (size_t)b * 1024 + u;
                float i_ = sigm(acc[mi][0][r] + bi_);
                float f_ = sigm(acc[mi][1][r] + bf_);
                float g_ = tanh_fast(acc[mi][2][r] + bg_);
                float o_ = sigm(acc[mi][3][r] + bo_);
                float c2 = f_ * cc[ci] + i_ * g_;
                cc[ci] = c2;
                hc_w[(size_t)(mt * 32 + fragk) * 512 + (size_t)((quad * 4 + r) + lanehi) * 8 + j]
                    = f2bf(o_ * tanh_fast(c2));
            }
        }
    }
}

// ---------------------------------------------------------------------------
// head_v3: out(256,32000) = hc(frag) @ bf16(Wout)^T + bout.
// ---------------------------------------------------------------------------
__global__ __launch_bounds__(256)
void head_v3(const u16* __restrict__ A,        // (256,1024) bf16 frag, NKC=32
             const float* __restrict__ W,      // (32000,1024) fp32
             const float* __restrict__ bias,
             float* __restrict__ out)          // (256,32000) fp32
{
    __shared__ __align__(16) u16 Bsh[2][2][4][512];   // 16 KB
    const int tid = threadIdx.x;
    const int w = tid >> 6, lane = tid & 63;
    const int l15 = lane & 15, quad = lane >> 4;
    const int bid = blockIdx.x;
    const int ntw = bid * 4 + w;                       // staged n-tile

    const float* wsrc = W + (size_t)(ntw * 16 + l15) * 1024 + (size_t)quad * 8;
    const u16* ha[4];
#pragma unroll
    for (int mi = 0; mi < 4; ++mi)
        ha[mi] = A + ((size_t)((w * 4 + mi) * 32)) * 512 + (size_t)lane * 8;

    f32x4 acc[4][4];
#pragma unroll
    for (int mi = 0; mi < 4; ++mi)
#pragma unroll
        for (int nt = 0; nt < 4; ++nt) acc[mi][nt] = {0.f, 0.f, 0.f, 0.f};

    {
        bf16x8 s0 = ld_cvt8(wsrc);
        bf16x8 s1 = ld_cvt8(wsrc + 32);
        *(bf16x8*)&Bsh[0][0][w][(size_t)lane * 8] = s0;
        *(bf16x8*)&Bsh[0][1][w][(size_t)lane * 8] = s1;
        __syncthreads();
    }
    for (int p = 0; p < 16; ++p) {
        const int cur = p & 1, nxt = cur ^ 1;
        bf16x8 sa, sb;
        const bool pre = (p + 1 < 16);
        if (pre) {
            sa = ld_cvt8(wsrc + (size_t)(2 * p + 2) * 32);
            sb = ld_cvt8(wsrc + (size_t)(2 * p + 3) * 32);
        }
        bf16x8 a0[4], a1[4];
#pragma unroll
        for (int mi = 0; mi < 4; ++mi) {
            a0[mi] = *(const bf16x8*)(ha[mi] + (size_t)(2 * p) * 512);
            a1[mi] = *(const bf16x8*)(ha[mi] + (size_t)(2 * p + 1) * 512);
        }
#pragma unroll
        for (int nt = 0; nt < 4; ++nt) {
            bf16x8 b0 = *(const bf16x8*)&Bsh[cur][0][nt][(size_t)lane * 8];
            bf16x8 b1 = *(const bf16x8*)&Bsh[cur][1][nt][(size_t)lane * 8];
#pragma unroll
            for (int mi = 0; mi < 4; ++mi) {
                acc[mi][nt] = MFMA(a0[mi], b0, acc[mi][nt]);
                acc[mi][nt] = MFMA(a1[mi], b1, acc[mi][nt]);
            }
        }
        if (pre) {
            *(bf16x8*)&Bsh[nxt][0][w][(size_t)lane * 8] = sa;
            *(bf16x8*)&Bsh[nxt][1][w][(size_t)lane * 8] = sb;
        }
        __syncthreads();
    }

#pragma unroll
    for (int nt = 0; nt < 4; ++nt) {
        const int n = (bid * 4 + nt) * 16 + l15;
        const float bv = bias[n];
#pragma unroll
        for (int mi = 0; mi < 4; ++mi) {
            const int mt = w * 4 + mi;
#pragma unroll
            for (int r = 0; r < 4; ++r)
                out[(size_t)(mt * 16 + quad * 4 + r) * VV + n] = acc[mi][nt][r] + bv;
        }
    }
}

extern "C" void kernel_launch(void* const* d_in, const int* in_sizes, int n_in,
                              void* d_out, int out_size, void* d_ws, size_t ws_size,
                              hipStream_t stream) {
    const int*   x     = (const int*)d_in[0];
    const float* W_emb = (const float*)d_in[1];
    const float* Wih_f = (const float*)d_in[2];
    const float* Whh_f = (const float*)d_in[3];
    const float* bih_f = (const float*)d_in[4];
    const float* bhh_f = (const float*)d_in[5];
    const float* Wih_b = (const float*)d_in[6];
    const float* Whh_b = (const float*)d_in[7];
    const float* bih_b = (const float*)d_in[8];
    const float* bhh_b = (const float*)d_in[9];
    const float* Wih_c = (const float*)d_in[10];
    const float* Whh_c = (const float*)d_in[11];
    const float* bih_c = (const float*)d_in[12];
    const float* bhh_c = (const float*)d_in[13];
    const float* Wout  = (const float*)d_in[14];
    const float* bout  = (const float*)d_in[15];
    const float* h0f   = (const float*)d_in[16];
    const float* c0f   = (const float*)d_in[17];
    const float* h0b   = (const float*)d_in[18];
    const float* c0b   = (const float*)d_in[19];
    const float* h0c   = (const float*)d_in[20];
    const float* c0c   = (const float*)d_in[21];

    // ws bump allocation (~44 MiB), all 16B-aligned
    char* p = (char*)d_ws;
    u16* Wfsw = (u16*)p; p += (size_t)2048 * 1024 * 2;          // 4 MB
    u16* Wbsw = (u16*)p; p += (size_t)2048 * 1024 * 2;          // 4 MB
    u16* Wcsw = (u16*)p; p += (size_t)4096 * 2048 * 2;          // 16 MB
    u16* Xfrag = (u16*)p; p += (size_t)8388608 * 2;             // 16 MB
    float* bsf = (float*)p; p += 2048 * 4;
    float* bsb = (float*)p; p += 2048 * 4;
    float* bsc = (float*)p; p += 4096 * 4;
    u16* hf[2]; hf[0] = (u16*)p; p += 131072 * 2; hf[1] = (u16*)p; p += 131072 * 2;
    u16* hb[2]; hb[0] = (u16*)p; p += 131072 * 2; hb[1] = (u16*)p; p += 131072 * 2;
    u16* hc[2]; hc[0] = (u16*)p; p += 262144 * 2; hc[1] = (u16*)p; p += 262144 * 2;
    float* cf = (float*)p; p += 131072 * 4;
    float* cb = (float*)p; p += 131072 * 4;
    float* cc = (float*)p; p += 262144 * 4;

    pack_k<<<dim3(2560), dim3(256), 0, stream>>>(
        x, W_emb, Wih_f, Whh_f, Wih_b, Whh_b, Wih_c, Whh_c,
        Xfrag, Wfsw, Wbsw, Wcsw);
    init_k<<<dim3(1024), dim3(256), 0, stream>>>(
        bih_f, bhh_f, bih_b, bhh_b, bih_c, bhh_c,
        h0f, c0f, h0b, c0b, h0c, c0c,
        bsf, bsb, bsc, hf[0], hb[0], hc[0], cf, cb, cc);

    // persistent cooperative sequence kernel (all 65 step iterations)
    const u16* Xfrag_c = Xfrag; const u16* Wfsw_c = Wfsw;
    const u16* Wbsw_c = Wbsw;   const u16* Wcsw_c = Wcsw;
    const float* bsf_c = bsf; const float* bsb_c = bsb; const float* bsc_c = bsc;
    u16 *hf0p = hf[0], *hf1p = hf[1], *hb0p = hb[0], *hb1p = hb[1];
    u16 *hc0p = hc[0], *hc1p = hc[1];
    const float* c0f_c = c0f; const float* c0b_c = c0b; const float* c0c_c = c0c;
    void* kargs[] = {
        (void*)&Xfrag_c, (void*)&Wfsw_c, (void*)&Wbsw_c, (void*)&Wcsw_c,
        (void*)&bsf_c, (void*)&bsb_c, (void*)&bsc_c,
        (void*)&hf0p, (void*)&hf1p, (void*)&hb0p, (void*)&hb1p,
        (void*)&hc0p, (void*)&hc1p,
        (void*)&c0f_c, (void*)&c0b_c, (void*)&c0c_c };
    hipError_t ce = hipLaunchCooperativeKernel((void*)seq_k, dim3(256), dim3(256),
                                               kargs, 0, stream);
    if (ce != hipSuccess) {
        // fallback: legacy 65-launch loop
        for (int t = 0; t <= SS; ++t) {
            step_k<<<dim3(256), dim3(256), 0, stream>>>(
                Xfrag, Wfsw, Wbsw, Wcsw, bsf, bsb, bsc,
                hf[t & 1], hf[(t + 1) & 1], cf,
                hb[t & 1], hb[(t + 1) & 1], cb,
                hc[(t + 1) & 1], hc[t & 1], cc, t);
        }
    }
    // final comb(63) wrote hc[0]
    head_v3<<<dim3(500), dim3(256), 0, stream>>>(hc[0], Wout, bout, (float*)d_out);
}

// Round 4
// 1461.841 us; speedup vs baseline: 2.3896x; 2.3896x over previous
//
#include <hip/hip_runtime.h>

#define BB 256
#define SS 64
#define HH 512
#define VV 32000

typedef unsigned short u16;
typedef __attribute__((ext_vector_type(8))) short bf16x8;   // 8 bf16 = 4 VGPRs
typedef __attribute__((ext_vector_type(4))) float f32x4;    // MFMA 16x16 C/D

__device__ __forceinline__ float sigm(float x) { return 1.0f / (1.0f + __expf(-x)); }
__device__ __forceinline__ float tanh_fast(float x) { return 1.0f - 2.0f / (__expf(2.0f * x) + 1.0f); }
__device__ __forceinline__ u16 f2bf(float f) {              // RNE fp32 -> bf16
    unsigned u = __float_as_uint(f);
    return (u16)((u + 0x7fffu + ((u >> 16) & 1u)) >> 16);
}
__device__ __forceinline__ bf16x8 ld_cvt8(const float* s) { // 8 fp32 -> bf16x8
    float4 v0 = *(const float4*)s, v1 = *(const float4*)(s + 4);
    bf16x8 b;
    b[0] = (short)f2bf(v0.x); b[1] = (short)f2bf(v0.y);
    b[2] = (short)f2bf(v0.z); b[3] = (short)f2bf(v0.w);
    b[4] = (short)f2bf(v1.x); b[5] = (short)f2bf(v1.y);
    b[6] = (short)f2bf(v1.z); b[7] = (short)f2bf(v1.w);
    return b;
}

#define MFMA(a, b, c) __builtin_amdgcn_mfma_f32_16x16x32_bf16(a, b, c, 0, 0, 0)

// ---------------------------------------------------------------------------
// pack_k: one-time swizzle into MFMA fragment layouts (wave-task based).
//  Xfrag  [s][mt][kc][lane][8]            : embedded seq, A-frag order, 16 MB
//  Wfsw/Wbsw [ut][kc 0..31][g][lane][8]   : fused [Wih|Whh] f/b, 4 MB each
//  Wcsw   [ut][kc 0..63][g][lane][8]      : fused [Wih_c|Whh_c], 16 MB
// ---------------------------------------------------------------------------
__global__ __launch_bounds__(256)
void pack_k(const int* __restrict__ x, const float* __restrict__ W_emb,
            const float* __restrict__ Wih_f, const float* __restrict__ Whh_f,
            const float* __restrict__ Wih_b, const float* __restrict__ Whh_b,
            const float* __restrict__ Wih_c, const float* __restrict__ Whh_c,
            u16* __restrict__ Xfrag, u16* __restrict__ Wfsw,
            u16* __restrict__ Wbsw, u16* __restrict__ Wcsw)
{
    const int lane = threadIdx.x & 63;
    const int l15 = lane & 15, quad = lane >> 4;
    const int gw0 = blockIdx.x * 4 + (threadIdx.x >> 6);
    const int nw = gridDim.x * 4;
    for (int task = gw0; task < 40960; task += nw) {
        const float* src; u16* dst; float scale = 1.f;
        if (task < 16384) {                         // Xfrag: (s, mt, kc)
            int s = task >> 8, rem = task & 255, mt = rem >> 4, kc = rem & 15;
            int b = mt * 16 + l15;
            int tok = x[s * 256 + b];               // raw reshape: row = s*256+b
            scale = (tok == 0) ? 0.f : 1.f;         // padding_idx=0
            src = W_emb + (size_t)tok * 512 + kc * 32 + quad * 8;
            dst = Xfrag + ((size_t)(s * 16 + mt) * 16 + kc) * 512 + (size_t)lane * 8;
        } else if (task < 24576) {                  // Wf / Wb: (which, ut, kc, g)
            int e = task - 16384;
            int which = e >> 12; e &= 4095;
            int ut = e >> 7, rem = e & 127, kc = rem >> 2, g = rem & 3;
            int row = g * 512 + ut * 16 + l15;
            int k0 = kc * 32 + quad * 8;
            const float* Wih = which ? Wih_b : Wih_f;
            const float* Whh = which ? Whh_b : Whh_f;
            src = (k0 < 512) ? (Wih + (size_t)row * 512 + k0)
                             : (Whh + (size_t)row * 512 + (k0 - 512));
            u16* W = which ? Wbsw : Wfsw;
            dst = W + ((size_t)(ut * 32 + kc) * 4 + g) * 512 + (size_t)lane * 8;
        } else {                                    // Wc: (ut, kc, g)
            int e = task - 24576;
            int ut = e >> 8, rem = e & 255, kc = rem >> 2, g = rem & 3;
            int row = g * 1024 + ut * 16 + l15;
            int k0 = kc * 32 + quad * 8;
            src = (k0 < 1024) ? (Wih_c + (size_t)row * 1024 + k0)
                              : (Whh_c + (size_t)row * 1024 + (k0 - 1024));
            dst = Wcsw + ((size_t)(ut * 64 + kc) * 4 + g) * 512 + (size_t)lane * 8;
        }
        float4 v0 = *(const float4*)src;
        float4 v1 = *(const float4*)(src + 4);
        bf16x8 o;
        o[0] = (short)f2bf(v0.x * scale); o[1] = (short)f2bf(v0.y * scale);
        o[2] = (short)f2bf(v0.z * scale); o[3] = (short)f2bf(v0.w * scale);
        o[4] = (short)f2bf(v1.x * scale); o[5] = (short)f2bf(v1.y * scale);
        o[6] = (short)f2bf(v1.z * scale); o[7] = (short)f2bf(v1.w * scale);
        *(bf16x8*)dst = o;
    }
}

// ---------------------------------------------------------------------------
// init_k: bias sums + initial states. h0 -> bf16 A-FRAGMENT layout, c -> fp32.
// ---------------------------------------------------------------------------
__global__ __launch_bounds__(256)
void init_k(const float* __restrict__ bih_f, const float* __restrict__ bhh_f,
            const float* __restrict__ bih_b, const float* __restrict__ bhh_b,
            const float* __restrict__ bih_c, const float* __restrict__ bhh_c,
            const float* __restrict__ h0f, const float* __restrict__ c0f,
            const float* __restrict__ h0b, const float* __restrict__ c0b,
            const float* __restrict__ h0c, const float* __restrict__ c0c,
            float* __restrict__ bsf, float* __restrict__ bsb, float* __restrict__ bsc,
            u16* __restrict__ hf0, u16* __restrict__ hb0, u16* __restrict__ hc0,
            float* __restrict__ cf, float* __restrict__ cb, float* __restrict__ cc)
{
    const int gid = blockIdx.x * 256 + threadIdx.x;
    if (gid < 2048)       bsf[gid] = bih_f[gid] + bhh_f[gid];
    else if (gid < 4096)  { int e = gid - 2048; bsb[e] = bih_b[e] + bhh_b[e]; }
    else if (gid < 8192)  { int e = gid - 4096; bsc[e] = bih_c[e] + bhh_c[e]; }
    const int stride = gridDim.x * 256;
    for (int i = gid; i < 131072; i += stride) {
        int b = i >> 9, k = i & 511;
        int dst = ((b >> 4) * 16 + (k >> 5)) * 512 + (((b & 15) + (((k >> 3) & 3) << 4)) << 3) + (k & 7);
        hf0[dst] = f2bf(h0f[i]);
        hb0[dst] = f2bf(h0b[i]);
        cf[i] = c0f[i];
        cb[i] = c0b[i];
    }
    for (int i = gid; i < 262144; i += stride) {
        int b = i >> 10, k = i & 1023;
        int dst = ((b >> 4) * 32 + (k >> 5)) * 512 + (((b & 15) + (((k >> 3) & 3) << 4)) << 3) + (k & 7);
        hc0[dst] = f2bf(h0c[i]);
        cc[i] = c0c[i];
    }
}

// ---------------------------------------------------------------------------
// step_k v5: same 256-block role map as the verified v4, but the GEMM period
// loop is software-pipelined: A-fragments prefetched 2 periods ahead (3-set
// register rotation), W staged global->reg 2 periods ahead, ds_write after
// the barrier. Global loads cross barriers legally (read-only buffers);
// per-period exposed latency drops from ~load-latency to ~LDS/barrier cost.
// FP accumulation order identical to v4.
// ---------------------------------------------------------------------------
__global__ __launch_bounds__(256)
void step_k(const u16* __restrict__ Xfrag,
            const u16* __restrict__ Wfsw, const u16* __restrict__ Wbsw,
            const u16* __restrict__ Wcsw,
            const float* __restrict__ bsf, const float* __restrict__ bsb,
            const float* __restrict__ bsc,
            const u16* __restrict__ hf_r, u16* __restrict__ hf_w, float* __restrict__ cf,
            const u16* __restrict__ hb_r, u16* __restrict__ hb_w, float* __restrict__ cb,
            const u16* __restrict__ hc_r, u16* __restrict__ hc_w, float* __restrict__ cc,
            int t)
{
    __shared__ __align__(16) u16 Bsh[2][2][4][512];   // 16 KB, double-buffered
    const int tid = threadIdx.x;
    const int w = tid >> 6, lane = tid & 63;
    const int l15 = lane & 15, quad = lane >> 4;
    const int xcd = blockIdx.x & 7, slot = blockIdx.x >> 3;
    const f32x4 z = {0.f, 0.f, 0.f, 0.f};

    if (slot < 16) {
        // ---------------- fb cells, step t (16 periods, K=1024) ----------------
        if (t >= SS) return;
        const int mh = slot & 1, cell = xcd >> 2;
        const int ut = (xcd & 3) * 8 + (slot >> 1);
        const int mt0 = mh * 8 + w * 2;
        const u16* Wsw = cell ? Wbsw : Wfsw;
        const float* bs = cell ? bsb : bsf;
        const u16* h_r = cell ? hb_r : hf_r;
        u16* h_w = cell ? hb_w : hf_w;
        float* c = cell ? cb : cf;
        const int s2 = cell ? (SS - 1 - t) : t;

        const u16* wstage = Wsw + (size_t)ut * 65536 + (size_t)w * 512 + (size_t)lane * 8;
        const u16* xb0 = Xfrag + ((size_t)(s2 * 16 + mt0) * 16) * 512 + (size_t)lane * 8;
        const u16* hp0 = h_r + ((size_t)(mt0 * 16)) * 512 + (size_t)lane * 8;

        f32x4 acc[2][4];
#pragma unroll
        for (int mi = 0; mi < 2; ++mi)
#pragma unroll
            for (int g = 0; g < 4; ++g) acc[mi][g] = z;

#define AFB(f) (((f) < 16) ? (xb0 + (size_t)(f) * 512) : (hp0 + (size_t)((f) - 16) * 512))
        bf16x8 aA0[3], aA1[3], aB0[3], aB1[3];
        {   // prologue: stage W periods 0,1 into Bsh[0],Bsh[1]; A periods 0,1
            bf16x8 w00 = *(const bf16x8*)(wstage);
            bf16x8 w01 = *(const bf16x8*)(wstage + 2048);
            bf16x8 w10 = *(const bf16x8*)(wstage + 2 * 2048);
            bf16x8 w11 = *(const bf16x8*)(wstage + 3 * 2048);
            const u16* f0 = AFB(0);  const u16* f1 = AFB(1);
            const u16* f2 = AFB(2);  const u16* f3 = AFB(3);
            aA0[0] = *(const bf16x8*)f0; aA1[0] = *(const bf16x8*)(f0 + 8192);
            aB0[0] = *(const bf16x8*)f1; aB1[0] = *(const bf16x8*)(f1 + 8192);
            aA0[1] = *(const bf16x8*)f2; aA1[1] = *(const bf16x8*)(f2 + 8192);
            aB0[1] = *(const bf16x8*)f3; aB1[1] = *(const bf16x8*)(f3 + 8192);
            *(bf16x8*)&Bsh[0][0][w][(size_t)lane * 8] = w00;
            *(bf16x8*)&Bsh[0][1][w][(size_t)lane * 8] = w01;
            *(bf16x8*)&Bsh[1][0][w][(size_t)lane * 8] = w10;
            *(bf16x8*)&Bsh[1][1][w][(size_t)lane * 8] = w11;
            __syncthreads();
        }
#pragma unroll
        for (int p = 0; p < 16; ++p) {
            const int s = p % 3, sn = (p + 2) % 3, cur = p & 1;
            bf16x8 wr0, wr1;
            const bool pre = (p + 2 < 16);
            if (pre) {
                wr0 = *(const bf16x8*)(wstage + (size_t)(2 * p + 4) * 2048);
                wr1 = *(const bf16x8*)(wstage + (size_t)(2 * p + 5) * 2048);
                const u16* f0 = AFB(2 * p + 4);
                const u16* f1 = AFB(2 * p + 5);
                aA0[sn] = *(const bf16x8*)f0; aA1[sn] = *(const bf16x8*)(f0 + 8192);
                aB0[sn] = *(const bf16x8*)f1; aB1[sn] = *(const bf16x8*)(f1 + 8192);
            }
#pragma unroll
            for (int g = 0; g < 4; ++g) {
                bf16x8 b0 = *(const bf16x8*)&Bsh[cur][0][g][(size_t)lane * 8];
                bf16x8 b1 = *(const bf16x8*)&Bsh[cur][1][g][(size_t)lane * 8];
                acc[0][g] = MFMA(aA0[s], b0, acc[0][g]);
                acc[1][g] = MFMA(aA1[s], b0, acc[1][g]);
                acc[0][g] = MFMA(aB0[s], b1, acc[0][g]);
                acc[1][g] = MFMA(aB1[s], b1, acc[1][g]);
            }
            __syncthreads();
            if (pre) {
                *(bf16x8*)&Bsh[cur][0][w][(size_t)lane * 8] = wr0;
                *(bf16x8*)&Bsh[cur][1][w][(size_t)lane * 8] = wr1;
            }
        }
#undef AFB

        const int u = ut * 16 + l15;
        const float bi_ = bs[u], bf_ = bs[512 + u], bg_ = bs[1024 + u], bo_ = bs[1536 + u];
        const int fragk = ut >> 1;
        const int lanehi = ((ut & 1) * 2 + (l15 >> 3)) << 4;
        const int j = l15 & 7;
#pragma unroll
        for (int mi = 0; mi < 2; ++mi) {
            const int mt = mt0 + mi;
#pragma unroll
            for (int r = 0; r < 4; ++r) {
                const int b = mt * 16 + quad * 4 + r;
                const size_t ci = (size_t)b * 512 + u;
                float i_ = sigm(acc[mi][0][r] + bi_);
                float f_ = sigm(acc[mi][1][r] + bf_);
                float g_ = tanh_fast(acc[mi][2][r] + bg_);
                float o_ = sigm(acc[mi][3][r] + bo_);
                float c2 = f_ * c[ci] + i_ * g_;
                c[ci] = c2;
                h_w[(size_t)(mt * 16 + fragk) * 512 + (size_t)((quad * 4 + r) + lanehi) * 8 + j]
                    = f2bf(o_ * tanh_fast(c2));
            }
        }
    } else {
        // ---------------- combiner, step t-1 (32 periods, K=2048) ----------------
        if (t == 0) return;
        const int cs = slot - 16;
        const int mh = cs & 1;
        const int ut = xcd * 8 + (cs >> 1);
        const int mt0 = mh * 8 + w * 2;

        const u16* wstage = Wcsw + (size_t)ut * 131072 + (size_t)w * 512 + (size_t)lane * 8;
        const u16* hfa = hf_r + ((size_t)(mt0 * 16)) * 512 + (size_t)lane * 8;
        const u16* hba = hb_r + ((size_t)(mt0 * 16)) * 512 + (size_t)lane * 8;
        const u16* hca = hc_r + ((size_t)(mt0 * 32)) * 512 + (size_t)lane * 8;

        f32x4 acc[2][4];
#pragma unroll
        for (int mi = 0; mi < 2; ++mi)
#pragma unroll
            for (int g = 0; g < 4; ++g) acc[mi][g] = z;

#define ACB(f)  (((f) < 16) ? (hfa + (size_t)(f) * 512) \
               : ((f) < 32) ? (hba + (size_t)((f) - 16) * 512) \
                            : (hca + (size_t)((f) - 32) * 512))
#define ACB1(f) (((f) < 32) ? 8192 : 16384)
        bf16x8 aA0[3], aA1[3], aB0[3], aB1[3];
        {   // prologue
            bf16x8 w00 = *(const bf16x8*)(wstage);
            bf16x8 w01 = *(const bf16x8*)(wstage + 2048);
            bf16x8 w10 = *(const bf16x8*)(wstage + 2 * 2048);
            bf16x8 w11 = *(const bf16x8*)(wstage + 3 * 2048);
            const u16* f0 = ACB(0);  const u16* f1 = ACB(1);
            const u16* f2 = ACB(2);  const u16* f3 = ACB(3);
            aA0[0] = *(const bf16x8*)f0; aA1[0] = *(const bf16x8*)(f0 + ACB1(0));
            aB0[0] = *(const bf16x8*)f1; aB1[0] = *(const bf16x8*)(f1 + ACB1(1));
            aA0[1] = *(const bf16x8*)f2; aA1[1] = *(const bf16x8*)(f2 + ACB1(2));
            aB0[1] = *(const bf16x8*)f3; aB1[1] = *(const bf16x8*)(f3 + ACB1(3));
            *(bf16x8*)&Bsh[0][0][w][(size_t)lane * 8] = w00;
            *(bf16x8*)&Bsh[0][1][w][(size_t)lane * 8] = w01;
            *(bf16x8*)&Bsh[1][0][w][(size_t)lane * 8] = w10;
            *(bf16x8*)&Bsh[1][1][w][(size_t)lane * 8] = w11;
            __syncthreads();
        }
#pragma unroll
        for (int p = 0; p < 32; ++p) {
            const int s = p % 3, sn = (p + 2) % 3, cur = p & 1;
            bf16x8 wr0, wr1;
            const bool pre = (p + 2 < 32);
            if (pre) {
                wr0 = *(const bf16x8*)(wstage + (size_t)(2 * p + 4) * 2048);
                wr1 = *(const bf16x8*)(wstage + (size_t)(2 * p + 5) * 2048);
                const u16* f0 = ACB(2 * p + 4);
                const u16* f1 = ACB(2 * p + 5);
                aA0[sn] = *(const bf16x8*)f0; aA1[sn] = *(const bf16x8*)(f0 + ACB1(2 * p + 4));
                aB0[sn] = *(const bf16x8*)f1; aB1[sn] = *(const bf16x8*)(f1 + ACB1(2 * p + 5));
            }
#pragma unroll
            for (int g = 0; g < 4; ++g) {
                bf16x8 b0 = *(const bf16x8*)&Bsh[cur][0][g][(size_t)lane * 8];
                bf16x8 b1 = *(const bf16x8*)&Bsh[cur][1][g][(size_t)lane * 8];
                acc[0][g] = MFMA(aA0[s], b0, acc[0][g]);
                acc[1][g] = MFMA(aA1[s], b0, acc[1][g]);
                acc[0][g] = MFMA(aB0[s], b1, acc[0][g]);
                acc[1][g] = MFMA(aB1[s], b1, acc[1][g]);
            }
            __syncthreads();
            if (pre) {
                *(bf16x8*)&Bsh[cur][0][w][(size_t)lane * 8] = wr0;
                *(bf16x8*)&Bsh[cur][1][w][(size_t)lane * 8] = wr1;
            }
        }
#undef ACB
#undef ACB1

        const int u = ut * 16 + l15;
        const float bi_ = bsc[u], bf_ = bsc[1024 + u], bg_ = bsc[2048 + u], bo_ = bsc[3072 + u];
        const int fragk = ut >> 1;
        const int lanehi = ((ut & 1) * 2 + (l15 >> 3)) << 4;
        const int j = l15 & 7;
#pragma unroll
        for (int mi = 0; mi < 2; ++mi) {
            const int mt = mt0 + mi;
#pragma unroll
            for (int r = 0; r < 4; ++r) {
                const int b = mt * 16 + quad * 4 + r;
                const size_t ci = (size_t)b * 1024 + u;
                float i_ = sigm(acc[mi][0][r] + bi_);
                float f_ = sigm(acc[mi][1][r] + bf_);
                float g_ = tanh_fast(acc[mi][2][r] + bg_);
                float o_ = sigm(acc[mi][3][r] + bo_);
                float c2 = f_ * cc[ci] + i_ * g_;
                cc[ci] = c2;
                hc_w[(size_t)(mt * 32 + fragk) * 512 + (size_t)((quad * 4 + r) + lanehi) * 8 + j]
                    = f2bf(o_ * tanh_fast(c2));
            }
        }
    }
}

// ---------------------------------------------------------------------------
// head_v3: out(256,32000) = hc(frag) @ bf16(Wout)^T + bout.
// ---------------------------------------------------------------------------
__global__ __launch_bounds__(256)
void head_v3(const u16* __restrict__ A,        // (256,1024) bf16 frag, NKC=32
             const float* __restrict__ W,      // (32000,1024) fp32
             const float* __restrict__ bias,
             float* __restrict__ out)          // (256,32000) fp32
{
    __shared__ __align__(16) u16 Bsh[2][2][4][512];   // 16 KB
    const int tid = threadIdx.x;
    const int w = tid >> 6, lane = tid & 63;
    const int l15 = lane & 15, quad = lane >> 4;
    const int bid = blockIdx.x;
    const int ntw = bid * 4 + w;                       // staged n-tile

    const float* wsrc = W + (size_t)(ntw * 16 + l15) * 1024 + (size_t)quad * 8;
    const u16* ha[4];
#pragma unroll
    for (int mi = 0; mi < 4; ++mi)
        ha[mi] = A + ((size_t)((w * 4 + mi) * 32)) * 512 + (size_t)lane * 8;

    f32x4 acc[4][4];
#pragma unroll
    for (int mi = 0; mi < 4; ++mi)
#pragma unroll
        for (int nt = 0; nt < 4; ++nt) acc[mi][nt] = {0.f, 0.f, 0.f, 0.f};

    {
        bf16x8 s0 = ld_cvt8(wsrc);
        bf16x8 s1 = ld_cvt8(wsrc + 32);
        *(bf16x8*)&Bsh[0][0][w][(size_t)lane * 8] = s0;
        *(bf16x8*)&Bsh[0][1][w][(size_t)lane * 8] = s1;
        __syncthreads();
    }
    for (int p = 0; p < 16; ++p) {
        const int cur = p & 1, nxt = cur ^ 1;
        bf16x8 sa, sb;
        const bool pre = (p + 1 < 16);
        if (pre) {
            sa = ld_cvt8(wsrc + (size_t)(2 * p + 2) * 32);
            sb = ld_cvt8(wsrc + (size_t)(2 * p + 3) * 32);
        }
        bf16x8 a0[4], a1[4];
#pragma unroll
        for (int mi = 0; mi < 4; ++mi) {
            a0[mi] = *(const bf16x8*)(ha[mi] + (size_t)(2 * p) * 512);
            a1[mi] = *(const bf16x8*)(ha[mi] + (size_t)(2 * p + 1) * 512);
        }
#pragma unroll
        for (int nt = 0; nt < 4; ++nt) {
            bf16x8 b0 = *(const bf16x8*)&Bsh[cur][0][nt][(size_t)lane * 8];
            bf16x8 b1 = *(const bf16x8*)&Bsh[cur][1][nt][(size_t)lane * 8];
#pragma unroll
            for (int mi = 0; mi < 4; ++mi) {
                acc[mi][nt] = MFMA(a0[mi], b0, acc[mi][nt]);
                acc[mi][nt] = MFMA(a1[mi], b1, acc[mi][nt]);
            }
        }
        if (pre) {
            *(bf16x8*)&Bsh[nxt][0][w][(size_t)lane * 8] = sa;
            *(bf16x8*)&Bsh[nxt][1][w][(size_t)lane * 8] = sb;
        }
        __syncthreads();
    }

#pragma unroll
    for (int nt = 0; nt < 4; ++nt) {
        const int n = (bid * 4 + nt) * 16 + l15;
        const float bv = bias[n];
#pragma unroll
        for (int mi = 0; mi < 4; ++mi) {
            const int mt = w * 4 + mi;
#pragma unroll
            for (int r = 0; r < 4; ++r)
                out[(size_t)(mt * 16 + quad * 4 + r) * VV + n] = acc[mi][nt][r] + bv;
        }
    }
}

extern "C" void kernel_launch(void* const* d_in, const int* in_sizes, int n_in,
                              void* d_out, int out_size, void* d_ws, size_t ws_size,
                              hipStream_t stream) {
    const int*   x     = (const int*)d_in[0];
    const float* W_emb = (const float*)d_in[1];
    const float* Wih_f = (const float*)d_in[2];
    const float* Whh_f = (const float*)d_in[3];
    const float* bih_f = (const float*)d_in[4];
    const float* bhh_f = (const float*)d_in[5];
    const float* Wih_b = (const float*)d_in[6];
    const float* Whh_b = (const float*)d_in[7];
    const float* bih_b = (const float*)d_in[8];
    const float* bhh_b = (const float*)d_in[9];
    const float* Wih_c = (const float*)d_in[10];
    const float* Whh_c = (const float*)d_in[11];
    const float* bih_c = (const float*)d_in[12];
    const float* bhh_c = (const float*)d_in[13];
    const float* Wout  = (const float*)d_in[14];
    const float* bout  = (const float*)d_in[15];
    const float* h0f   = (const float*)d_in[16];
    const float* c0f   = (const float*)d_in[17];
    const float* h0b   = (const float*)d_in[18];
    const float* c0b   = (const float*)d_in[19];
    const float* h0c   = (const float*)d_in[20];
    const float* c0c   = (const float*)d_in[21];

    // ws bump allocation (~44 MiB), all 16B-aligned
    char* p = (char*)d_ws;
    u16* Wfsw = (u16*)p; p += (size_t)2048 * 1024 * 2;          // 4 MB
    u16* Wbsw = (u16*)p; p += (size_t)2048 * 1024 * 2;          // 4 MB
    u16* Wcsw = (u16*)p; p += (size_t)4096 * 2048 * 2;          // 16 MB
    u16* Xfrag = (u16*)p; p += (size_t)8388608 * 2;             // 16 MB
    float* bsf = (float*)p; p += 2048 * 4;
    float* bsb = (float*)p; p += 2048 * 4;
    float* bsc = (float*)p; p += 4096 * 4;
    u16* hf[2]; hf[0] = (u16*)p; p += 131072 * 2; hf[1] = (u16*)p; p += 131072 * 2;
    u16* hb[2]; hb[0] = (u16*)p; p += 131072 * 2; hb[1] = (u16*)p; p += 131072 * 2;
    u16* hc[2]; hc[0] = (u16*)p; p += 262144 * 2; hc[1] = (u16*)p; p += 262144 * 2;
    float* cf = (float*)p; p += 131072 * 4;
    float* cb = (float*)p; p += 131072 * 4;
    float* cc = (float*)p; p += 262144 * 4;

    pack_k<<<dim3(2560), dim3(256), 0, stream>>>(
        x, W_emb, Wih_f, Whh_f, Wih_b, Whh_b, Wih_c, Whh_c,
        Xfrag, Wfsw, Wbsw, Wcsw);
    init_k<<<dim3(1024), dim3(256), 0, stream>>>(
        bih_f, bhh_f, bih_b, bhh_b, bih_c, bhh_c,
        h0f, c0f, h0b, c0b, h0c, c0c,
        bsf, bsb, bsc, hf[0], hb[0], hc[0], cf, cb, cc);

    // fb(s): reads h[s&1], writes h[(s+1)&1].  comb(s): reads hf/hb[(s+1)&1],
    // hc[s&1]; writes hc[(s+1)&1]. Launch t runs fb(t) + comb(t-1).
    for (int t = 0; t <= SS; ++t) {
        step_k<<<dim3(256), dim3(256), 0, stream>>>(
            Xfrag, Wfsw, Wbsw, Wcsw, bsf, bsb, bsc,
            hf[t & 1], hf[(t + 1) & 1], cf,
            hb[t & 1], hb[(t + 1) & 1], cb,
            hc[(t + 1) & 1], hc[t & 1], cc, t);
    }
    // final comb(63) wrote hc[0]
    head_v3<<<dim3(500), dim3(256), 0, stream>>>(hc[0], Wout, bout, (float*)d_out);
}

// Round 6
// 1185.393 us; speedup vs baseline: 2.9468x; 1.2332x over previous
//
#include <hip/hip_runtime.h>

#define BB 256
#define SS 64
#define HH 512
#define VV 32000

typedef unsigned short u16;
typedef __attribute__((ext_vector_type(8))) short bf16x8;   // 8 bf16 = 4 VGPRs
typedef __attribute__((ext_vector_type(4))) float f32x4;    // MFMA 16x16 C/D

__device__ __forceinline__ float sigm(float x) { return 1.0f / (1.0f + __expf(-x)); }
__device__ __forceinline__ float tanh_fast(float x) { return 1.0f - 2.0f / (__expf(2.0f * x) + 1.0f); }
__device__ __forceinline__ u16 f2bf(float f) {              // RNE fp32 -> bf16
    unsigned u = __float_as_uint(f);
    return (u16)((u + 0x7fffu + ((u >> 16) & 1u)) >> 16);
}
__device__ __forceinline__ bf16x8 ld_cvt8(const float* s) { // 8 fp32 -> bf16x8
    float4 v0 = *(const float4*)s, v1 = *(const float4*)(s + 4);
    bf16x8 b;
    b[0] = (short)f2bf(v0.x); b[1] = (short)f2bf(v0.y);
    b[2] = (short)f2bf(v0.z); b[3] = (short)f2bf(v0.w);
    b[4] = (short)f2bf(v1.x); b[5] = (short)f2bf(v1.y);
    b[6] = (short)f2bf(v1.z); b[7] = (short)f2bf(v1.w);
    return b;
}

#define MFMA(a, b, c) __builtin_amdgcn_mfma_f32_16x16x32_bf16(a, b, c, 0, 0, 0)

// ---------------------------------------------------------------------------
// pack_k: one-time swizzle into MFMA fragment layouts (wave-task based).
//  Xfrag  [s][mt][kc][lane][8]            : embedded seq, A-frag order, 16 MB
//  Wfsw/Wbsw [ut][kc 0..31][g][lane][8]   : fused [Wih|Whh] f/b, 4 MB each
//  Wcsw   [ut][kc 0..63][g][lane][8]      : fused [Wih_c|Whh_c], 16 MB
// ---------------------------------------------------------------------------
__global__ __launch_bounds__(256)
void pack_k(const int* __restrict__ x, const float* __restrict__ W_emb,
            const float* __restrict__ Wih_f, const float* __restrict__ Whh_f,
            const float* __restrict__ Wih_b, const float* __restrict__ Whh_b,
            const float* __restrict__ Wih_c, const float* __restrict__ Whh_c,
            u16* __restrict__ Xfrag, u16* __restrict__ Wfsw,
            u16* __restrict__ Wbsw, u16* __restrict__ Wcsw)
{
    const int lane = threadIdx.x & 63;
    const int l15 = lane & 15, quad = lane >> 4;
    const int gw0 = blockIdx.x * 4 + (threadIdx.x >> 6);
    const int nw = gridDim.x * 4;
    for (int task = gw0; task < 40960; task += nw) {
        const float* src; u16* dst; float scale = 1.f;
        if (task < 16384) {                         // Xfrag: (s, mt, kc)
            int s = task >> 8, rem = task & 255, mt = rem >> 4, kc = rem & 15;
            int b = mt * 16 + l15;
            int tok = x[s * 256 + b];               // raw reshape: row = s*256+b
            scale = (tok == 0) ? 0.f : 1.f;         // padding_idx=0
            src = W_emb + (size_t)tok * 512 + kc * 32 + quad * 8;
            dst = Xfrag + ((size_t)(s * 16 + mt) * 16 + kc) * 512 + (size_t)lane * 8;
        } else if (task < 24576) {                  // Wf / Wb: (which, ut, kc, g)
            int e = task - 16384;
            int which = e >> 12; e &= 4095;
            int ut = e >> 7, rem = e & 127, kc = rem >> 2, g = rem & 3;
            int row = g * 512 + ut * 16 + l15;
            int k0 = kc * 32 + quad * 8;
            const float* Wih = which ? Wih_b : Wih_f;
            const float* Whh = which ? Whh_b : Whh_f;
            src = (k0 < 512) ? (Wih + (size_t)row * 512 + k0)
                             : (Whh + (size_t)row * 512 + (k0 - 512));
            u16* W = which ? Wbsw : Wfsw;
            dst = W + ((size_t)(ut * 32 + kc) * 4 + g) * 512 + (size_t)lane * 8;
        } else {                                    // Wc: (ut, kc, g)
            int e = task - 24576;
            int ut = e >> 8, rem = e & 255, kc = rem >> 2, g = rem & 3;
            int row = g * 1024 + ut * 16 + l15;
            int k0 = kc * 32 + quad * 8;
            src = (k0 < 1024) ? (Wih_c + (size_t)row * 1024 + k0)
                              : (Whh_c + (size_t)row * 1024 + (k0 - 1024));
            dst = Wcsw + ((size_t)(ut * 64 + kc) * 4 + g) * 512 + (size_t)lane * 8;
        }
        float4 v0 = *(const float4*)src;
        float4 v1 = *(const float4*)(src + 4);
        bf16x8 o;
        o[0] = (short)f2bf(v0.x * scale); o[1] = (short)f2bf(v0.y * scale);
        o[2] = (short)f2bf(v0.z * scale); o[3] = (short)f2bf(v0.w * scale);
        o[4] = (short)f2bf(v1.x * scale); o[5] = (short)f2bf(v1.y * scale);
        o[6] = (short)f2bf(v1.z * scale); o[7] = (short)f2bf(v1.w * scale);
        *(bf16x8*)dst = o;
    }
}

// ---------------------------------------------------------------------------
// init_k: bias sums + initial states. h0 -> bf16 A-FRAGMENT layout, c -> fp32.
// ---------------------------------------------------------------------------
__global__ __launch_bounds__(256)
void init_k(const float* __restrict__ bih_f, const float* __restrict__ bhh_f,
            const float* __restrict__ bih_b, const float* __restrict__ bhh_b,
            const float* __restrict__ bih_c, const float* __restrict__ bhh_c,
            const float* __restrict__ h0f, const float* __restrict__ c0f,
            const float* __restrict__ h0b, const float* __restrict__ c0b,
            const float* __restrict__ h0c, const float* __restrict__ c0c,
            float* __restrict__ bsf, float* __restrict__ bsb, float* __restrict__ bsc,
            u16* __restrict__ hf0, u16* __restrict__ hb0, u16* __restrict__ hc0,
            float* __restrict__ cf, float* __restrict__ cb, float* __restrict__ cc)
{
    const int gid = blockIdx.x * 256 + threadIdx.x;
    if (gid < 2048)       bsf[gid] = bih_f[gid] + bhh_f[gid];
    else if (gid < 4096)  { int e = gid - 2048; bsb[e] = bih_b[e] + bhh_b[e]; }
    else if (gid < 8192)  { int e = gid - 4096; bsc[e] = bih_c[e] + bhh_c[e]; }
    const int stride = gridDim.x * 256;
    for (int i = gid; i < 131072; i += stride) {
        int b = i >> 9, k = i & 511;
        int dst = ((b >> 4) * 16 + (k >> 5)) * 512 + (((b & 15) + (((k >> 3) & 3) << 4)) << 3) + (k & 7);
        hf0[dst] = f2bf(h0f[i]);
        hb0[dst] = f2bf(h0b[i]);
        cf[i] = c0f[i];
        cb[i] = c0b[i];
    }
    for (int i = gid; i < 262144; i += stride) {
        int b = i >> 10, k = i & 1023;
        int dst = ((b >> 4) * 32 + (k >> 5)) * 512 + (((b & 15) + (((k >> 3) & 3) << 4)) << 3) + (k & 7);
        hc0[dst] = f2bf(h0c[i]);
        cc[i] = c0c[i];
    }
}

// ---------------------------------------------------------------------------
// step_k v6: 512 blocks (2/CU, 2 waves/SIMD), M split one level finer than v5.
//  slot = blockIdx>>3 (0..63), xcd = blockIdx&7.
//  slot<32 : fb cell, cell=xcd>>2, ut=(xcd&3)*8+(slot>>2), mq=slot&3
//  slot>=32: comb,    ut=xcd*8+((slot-32)>>2),             mq=(slot-32)&3
//  Block covers M-quarter (4 m-tiles); wave w owns mt = mq*4+w and stages
//  gate w's B to LDS. Software pipeline identical to v5 (A prefetch 2 periods
//  ahead, 3-set rotation; W global->reg 2 ahead, ds_write after barrier).
//  Per-XCD weight residency identical to v4/v5. Accumulation order per (b,u)
//  unchanged.
// ---------------------------------------------------------------------------
__global__ __launch_bounds__(256)
void step_k(const u16* __restrict__ Xfrag,
            const u16* __restrict__ Wfsw, const u16* __restrict__ Wbsw,
            const u16* __restrict__ Wcsw,
            const float* __restrict__ bsf, const float* __restrict__ bsb,
            const float* __restrict__ bsc,
            const u16* __restrict__ hf_r, u16* __restrict__ hf_w, float* __restrict__ cf,
            const u16* __restrict__ hb_r, u16* __restrict__ hb_w, float* __restrict__ cb,
            const u16* __restrict__ hc_r, u16* __restrict__ hc_w, float* __restrict__ cc,
            int t)
{
    __shared__ __align__(16) u16 Bsh[2][2][4][512];   // 16 KB, double-buffered
    const int tid = threadIdx.x;
    const int w = tid >> 6, lane = tid & 63;
    const int l15 = lane & 15, quad = lane >> 4;
    const int xcd = blockIdx.x & 7, slot = blockIdx.x >> 3;
    const f32x4 z = {0.f, 0.f, 0.f, 0.f};

    if (slot < 32) {
        // ---------------- fb cells, step t (16 periods, K=1024) ----------------
        if (t >= SS) return;
        const int cell = xcd >> 2;
        const int ut = (xcd & 3) * 8 + (slot >> 2);
        const int mq = slot & 3;
        const int mt = mq * 4 + w;                  // this wave's m-tile
        const u16* Wsw = cell ? Wbsw : Wfsw;
        const float* bs = cell ? bsb : bsf;
        const u16* h_r = cell ? hb_r : hf_r;
        u16* h_w = cell ? hb_w : hf_w;
        float* c = cell ? cb : cf;
        const int s2 = cell ? (SS - 1 - t) : t;

        const u16* wstage = Wsw + (size_t)ut * 65536 + (size_t)w * 512 + (size_t)lane * 8;
        const u16* xb0 = Xfrag + ((size_t)(s2 * 16 + mt) * 16) * 512 + (size_t)lane * 8;
        const u16* hp0 = h_r + ((size_t)(mt * 16)) * 512 + (size_t)lane * 8;

        f32x4 acc[4];
#pragma unroll
        for (int g = 0; g < 4; ++g) acc[g] = z;

#define AFB(f) (((f) < 16) ? (xb0 + (size_t)(f) * 512) : (hp0 + (size_t)((f) - 16) * 512))
        bf16x8 a0[3], a1[3];
        {   // prologue: stage W periods 0,1 into Bsh[0],Bsh[1]; A periods 0,1
            bf16x8 w00 = *(const bf16x8*)(wstage);
            bf16x8 w01 = *(const bf16x8*)(wstage + 2048);
            bf16x8 w10 = *(const bf16x8*)(wstage + 2 * 2048);
            bf16x8 w11 = *(const bf16x8*)(wstage + 3 * 2048);
            a0[0] = *(const bf16x8*)AFB(0); a1[0] = *(const bf16x8*)AFB(1);
            a0[1] = *(const bf16x8*)AFB(2); a1[1] = *(const bf16x8*)AFB(3);
            *(bf16x8*)&Bsh[0][0][w][(size_t)lane * 8] = w00;
            *(bf16x8*)&Bsh[0][1][w][(size_t)lane * 8] = w01;
            *(bf16x8*)&Bsh[1][0][w][(size_t)lane * 8] = w10;
            *(bf16x8*)&Bsh[1][1][w][(size_t)lane * 8] = w11;
            __syncthreads();
        }
#pragma unroll
        for (int p = 0; p < 16; ++p) {
            const int s = p % 3, sn = (p + 2) % 3, cur = p & 1;
            bf16x8 wr0, wr1;
            const bool pre = (p + 2 < 16);
            if (pre) {
                wr0 = *(const bf16x8*)(wstage + (size_t)(2 * p + 4) * 2048);
                wr1 = *(const bf16x8*)(wstage + (size_t)(2 * p + 5) * 2048);
                a0[sn] = *(const bf16x8*)AFB(2 * p + 4);
                a1[sn] = *(const bf16x8*)AFB(2 * p + 5);
            }
#pragma unroll
            for (int g = 0; g < 4; ++g) {
                bf16x8 b0 = *(const bf16x8*)&Bsh[cur][0][g][(size_t)lane * 8];
                bf16x8 b1 = *(const bf16x8*)&Bsh[cur][1][g][(size_t)lane * 8];
                acc[g] = MFMA(a0[s], b0, acc[g]);
                acc[g] = MFMA(a1[s], b1, acc[g]);
            }
            __syncthreads();
            if (pre) {
                *(bf16x8*)&Bsh[cur][0][w][(size_t)lane * 8] = wr0;
                *(bf16x8*)&Bsh[cur][1][w][(size_t)lane * 8] = wr1;
            }
        }
#undef AFB

        const int u = ut * 16 + l15;
        const float bi_ = bs[u], bf_ = bs[512 + u], bg_ = bs[1024 + u], bo_ = bs[1536 + u];
        const int fragk = ut >> 1;
        const int lanehi = ((ut & 1) * 2 + (l15 >> 3)) << 4;
        const int j = l15 & 7;
#pragma unroll
        for (int r = 0; r < 4; ++r) {
            const int b = mt * 16 + quad * 4 + r;
            const size_t ci = (size_t)b * 512 + u;
            float i_ = sigm(acc[0][r] + bi_);
            float f_ = sigm(acc[1][r] + bf_);
            float g_ = tanh_fast(acc[2][r] + bg_);
            float o_ = sigm(acc[3][r] + bo_);
            float c2 = f_ * c[ci] + i_ * g_;
            c[ci] = c2;
            h_w[(size_t)(mt * 16 + fragk) * 512 + (size_t)((quad * 4 + r) + lanehi) * 8 + j]
                = f2bf(o_ * tanh_fast(c2));
        }
    } else {
        // ---------------- combiner, step t-1 (32 periods, K=2048) ----------------
        if (t == 0) return;
        const int cs = slot - 32;
        const int ut = xcd * 8 + (cs >> 2);
        const int mq = cs & 3;
        const int mt = mq * 4 + w;

        const u16* wstage = Wcsw + (size_t)ut * 131072 + (size_t)w * 512 + (size_t)lane * 8;
        const u16* hfa = hf_r + ((size_t)(mt * 16)) * 512 + (size_t)lane * 8;
        const u16* hba = hb_r + ((size_t)(mt * 16)) * 512 + (size_t)lane * 8;
        const u16* hca = hc_r + ((size_t)(mt * 32)) * 512 + (size_t)lane * 8;

        f32x4 acc[4];
#pragma unroll
        for (int g = 0; g < 4; ++g) acc[g] = z;

#define ACB(f)  (((f) < 16) ? (hfa + (size_t)(f) * 512) \
               : ((f) < 32) ? (hba + (size_t)((f) - 16) * 512) \
                            : (hca + (size_t)((f) - 32) * 512))
        bf16x8 a0[3], a1[3];
        {   // prologue
            bf16x8 w00 = *(const bf16x8*)(wstage);
            bf16x8 w01 = *(const bf16x8*)(wstage + 2048);
            bf16x8 w10 = *(const bf16x8*)(wstage + 2 * 2048);
            bf16x8 w11 = *(const bf16x8*)(wstage + 3 * 2048);
            a0[0] = *(const bf16x8*)ACB(0); a1[0] = *(const bf16x8*)ACB(1);
            a0[1] = *(const bf16x8*)ACB(2); a1[1] = *(const bf16x8*)ACB(3);
            *(bf16x8*)&Bsh[0][0][w][(size_t)lane * 8] = w00;
            *(bf16x8*)&Bsh[0][1][w][(size_t)lane * 8] = w01;
            *(bf16x8*)&Bsh[1][0][w][(size_t)lane * 8] = w10;
            *(bf16x8*)&Bsh[1][1][w][(size_t)lane * 8] = w11;
            __syncthreads();
        }
#pragma unroll
        for (int p = 0; p < 32; ++p) {
            const int s = p % 3, sn = (p + 2) % 3, cur = p & 1;
            bf16x8 wr0, wr1;
            const bool pre = (p + 2 < 32);
            if (pre) {
                wr0 = *(const bf16x8*)(wstage + (size_t)(2 * p + 4) * 2048);
                wr1 = *(const bf16x8*)(wstage + (size_t)(2 * p + 5) * 2048);
                a0[sn] = *(const bf16x8*)ACB(2 * p + 4);
                a1[sn] = *(const bf16x8*)ACB(2 * p + 5);
            }
#pragma unroll
            for (int g = 0; g < 4; ++g) {
                bf16x8 b0 = *(const bf16x8*)&Bsh[cur][0][g][(size_t)lane * 8];
                bf16x8 b1 = *(const bf16x8*)&Bsh[cur][1][g][(size_t)lane * 8];
                acc[g] = MFMA(a0[s], b0, acc[g]);
                acc[g] = MFMA(a1[s], b1, acc[g]);
            }
            __syncthreads();
            if (pre) {
                *(bf16x8*)&Bsh[cur][0][w][(size_t)lane * 8] = wr0;
                *(bf16x8*)&Bsh[cur][1][w][(size_t)lane * 8] = wr1;
            }
        }
#undef ACB

        const int u = ut * 16 + l15;
        const float bi_ = bsc[u], bf_ = bsc[1024 + u], bg_ = bsc[2048 + u], bo_ = bsc[3072 + u];
        const int fragk = ut >> 1;
        const int lanehi = ((ut & 1) * 2 + (l15 >> 3)) << 4;
        const int j = l15 & 7;
#pragma unroll
        for (int r = 0; r < 4; ++r) {
            const int b = mt * 16 + quad * 4 + r;
            const size_t ci = (size_t)b * 1024 + u;
            float i_ = sigm(acc[0][r] + bi_);
            float f_ = sigm(acc[1][r] + bf_);
            float g_ = tanh_fast(acc[2][r] + bg_);
            float o_ = sigm(acc[3][r] + bo_);
            float c2 = f_ * cc[ci] + i_ * g_;
            cc[ci] = c2;
            hc_w[(size_t)(mt * 32 + fragk) * 512 + (size_t)((quad * 4 + r) + lanehi) * 8 + j]
                = f2bf(o_ * tanh_fast(c2));
        }
    }
}

// ---------------------------------------------------------------------------
// head_v3: out(256,32000) = hc(frag) @ bf16(Wout)^T + bout.
// ---------------------------------------------------------------------------
__global__ __launch_bounds__(256)
void head_v3(const u16* __restrict__ A,        // (256,1024) bf16 frag, NKC=32
             const float* __restrict__ W,      // (32000,1024) fp32
             const float* __restrict__ bias,
             float* __restrict__ out)          // (256,32000) fp32
{
    __shared__ __align__(16) u16 Bsh[2][2][4][512];   // 16 KB
    const int tid = threadIdx.x;
    const int w = tid >> 6, lane = tid & 63;
    const int l15 = lane & 15, quad = lane >> 4;
    const int bid = blockIdx.x;
    const int ntw = bid * 4 + w;                       // staged n-tile

    const float* wsrc = W + (size_t)(ntw * 16 + l15) * 1024 + (size_t)quad * 8;
    const u16* ha[4];
#pragma unroll
    for (int mi = 0; mi < 4; ++mi)
        ha[mi] = A + ((size_t)((w * 4 + mi) * 32)) * 512 + (size_t)lane * 8;

    f32x4 acc[4][4];
#pragma unroll
    for (int mi = 0; mi < 4; ++mi)
#pragma unroll
        for (int nt = 0; nt < 4; ++nt) acc[mi][nt] = {0.f, 0.f, 0.f, 0.f};

    {
        bf16x8 s0 = ld_cvt8(wsrc);
        bf16x8 s1 = ld_cvt8(wsrc + 32);
        *(bf16x8*)&Bsh[0][0][w][(size_t)lane * 8] = s0;
        *(bf16x8*)&Bsh[0][1][w][(size_t)lane * 8] = s1;
        __syncthreads();
    }
    for (int p = 0; p < 16; ++p) {
        const int cur = p & 1, nxt = cur ^ 1;
        bf16x8 sa, sb;
        const bool pre = (p + 1 < 16);
        if (pre) {
            sa = ld_cvt8(wsrc + (size_t)(2 * p + 2) * 32);
            sb = ld_cvt8(wsrc + (size_t)(2 * p + 3) * 32);
        }
        bf16x8 a0[4], a1[4];
#pragma unroll
        for (int mi = 0; mi < 4; ++mi) {
            a0[mi] = *(const bf16x8*)(ha[mi] + (size_t)(2 * p) * 512);
            a1[mi] = *(const bf16x8*)(ha[mi] + (size_t)(2 * p + 1) * 512);
        }
#pragma unroll
        for (int nt = 0; nt < 4; ++nt) {
            bf16x8 b0 = *(const bf16x8*)&Bsh[cur][0][nt][(size_t)lane * 8];
            bf16x8 b1 = *(const bf16x8*)&Bsh[cur][1][nt][(size_t)lane * 8];
#pragma unroll
            for (int mi = 0; mi < 4; ++mi) {
                acc[mi][nt] = MFMA(a0[mi], b0, acc[mi][nt]);
                acc[mi][nt] = MFMA(a1[mi], b1, acc[mi][nt]);
            }
        }
        if (pre) {
            *(bf16x8*)&Bsh[nxt][0][w][(size_t)lane * 8] = sa;
            *(bf16x8*)&Bsh[nxt][1][w][(size_t)lane * 8] = sb;
        }
        __syncthreads();
    }

#pragma unroll
    for (int nt = 0; nt < 4; ++nt) {
        const int n = (bid * 4 + nt) * 16 + l15;
        const float bv = bias[n];
#pragma unroll
        for (int mi = 0; mi < 4; ++mi) {
            const int mt = w * 4 + mi;
#pragma unroll
            for (int r = 0; r < 4; ++r)
                out[(size_t)(mt * 16 + quad * 4 + r) * VV + n] = acc[mi][nt][r] + bv;
        }
    }
}

extern "C" void kernel_launch(void* const* d_in, const int* in_sizes, int n_in,
                              void* d_out, int out_size, void* d_ws, size_t ws_size,
                              hipStream_t stream) {
    const int*   x     = (const int*)d_in[0];
    const float* W_emb = (const float*)d_in[1];
    const float* Wih_f = (const float*)d_in[2];
    const float* Whh_f = (const float*)d_in[3];
    const float* bih_f = (const float*)d_in[4];
    const float* bhh_f = (const float*)d_in[5];
    const float* Wih_b = (const float*)d_in[6];
    const float* Whh_b = (const float*)d_in[7];
    const float* bih_b = (const float*)d_in[8];
    const float* bhh_b = (const float*)d_in[9];
    const float* Wih_c = (const float*)d_in[10];
    const float* Whh_c = (const float*)d_in[11];
    const float* bih_c = (const float*)d_in[12];
    const float* bhh_c = (const float*)d_in[13];
    const float* Wout  = (const float*)d_in[14];
    const float* bout  = (const float*)d_in[15];
    const float* h0f   = (const float*)d_in[16];
    const float* c0f   = (const float*)d_in[17];
    const float* h0b   = (const float*)d_in[18];
    const float* c0b   = (const float*)d_in[19];
    const float* h0c   = (const float*)d_in[20];
    const float* c0c   = (const float*)d_in[21];

    // ws bump allocation (~44 MiB), all 16B-aligned
    char* p = (char*)d_ws;
    u16* Wfsw = (u16*)p; p += (size_t)2048 * 1024 * 2;          // 4 MB
    u16* Wbsw = (u16*)p; p += (size_t)2048 * 1024 * 2;          // 4 MB
    u16* Wcsw = (u16*)p; p += (size_t)4096 * 2048 * 2;          // 16 MB
    u16* Xfrag = (u16*)p; p += (size_t)8388608 * 2;             // 16 MB
    float* bsf = (float*)p; p += 2048 * 4;
    float* bsb = (float*)p; p += 2048 * 4;
    float* bsc = (float*)p; p += 4096 * 4;
    u16* hf[2]; hf[0] = (u16*)p; p += 131072 * 2; hf[1] = (u16*)p; p += 131072 * 2;
    u16* hb[2]; hb[0] = (u16*)p; p += 131072 * 2; hb[1] = (u16*)p; p += 131072 * 2;
    u16* hc[2]; hc[0] = (u16*)p; p += 262144 * 2; hc[1] = (u16*)p; p += 262144 * 2;
    float* cf = (float*)p; p += 131072 * 4;
    float* cb = (float*)p; p += 131072 * 4;
    float* cc = (float*)p; p += 262144 * 4;

    pack_k<<<dim3(2560), dim3(256), 0, stream>>>(
        x, W_emb, Wih_f, Whh_f, Wih_b, Whh_b, Wih_c, Whh_c,
        Xfrag, Wfsw, Wbsw, Wcsw);
    init_k<<<dim3(1024), dim3(256), 0, stream>>>(
        bih_f, bhh_f, bih_b, bhh_b, bih_c, bhh_c,
        h0f, c0f, h0b, c0b, h0c, c0c,
        bsf, bsb, bsc, hf[0], hb[0], hc[0], cf, cb, cc);

    // fb(s): reads h[s&1], writes h[(s+1)&1].  comb(s): reads hf/hb[(s+1)&1],
    // hc[s&1]; writes hc[(s+1)&1]. Launch t runs fb(t) + comb(t-1).
    for (int t = 0; t <= SS; ++t) {
        step_k<<<dim3(512), dim3(256), 0, stream>>>(
            Xfrag, Wfsw, Wbsw, Wcsw, bsf, bsb, bsc,
            hf[t & 1], hf[(t + 1) & 1], cf,
            hb[t & 1], hb[(t + 1) & 1], cb,
            hc[(t + 1) & 1], hc[t & 1], cc, t);
    }
    // final comb(63) wrote hc[0]
    head_v3<<<dim3(500), dim3(256), 0, stream>>>(hc[0], Wout, bout, (float*)d_out);
}